// Round 6
// baseline (902.475 us; speedup 1.0000x reference)
//
#include <hip/hip_runtime.h>

typedef unsigned short ushort_t;
typedef unsigned int uint32;

typedef float f32x4 __attribute__((ext_vector_type(4)));
typedef __bf16 bf16x8 __attribute__((ext_vector_type(8)));
typedef unsigned short us8 __attribute__((ext_vector_type(8)));
typedef unsigned short us4 __attribute__((ext_vector_type(4)));

#define TSEQ 2048
#define DMODEL 4096

__device__ __forceinline__ ushort_t f2bf(float f) {
  uint32 u = __builtin_bit_cast(uint32, f);
  u += 0x7FFFu + ((u >> 16) & 1u);   // RNE (no NaNs in this problem)
  return (ushort_t)(u >> 16);
}
__device__ __forceinline__ float bf2f(ushort_t u) {
  return __builtin_bit_cast(float, ((uint32)u) << 16);
}

__device__ __forceinline__ void gload_lds16(const void* g, void* l) {
  auto gp = (const __attribute__((address_space(1))) void*)g;
  auto lp = (__attribute__((address_space(3))) void*)l;
  __builtin_amdgcn_global_load_lds(gp, lp, 16, 0, 0);
}

// ---------------- cast fp32 -> bf16 (vectorized) ----------------
__global__ __launch_bounds__(256) void k_cast_bf16(const float* __restrict__ in,
                                                   ushort_t* __restrict__ out, int n4) {
  int g = blockIdx.x * 256 + threadIdx.x;
  if (g >= n4) return;
  float4 v = *(const float4*)(in + (size_t)g * 4);
  us4 o; o[0] = f2bf(v.x); o[1] = f2bf(v.y); o[2] = f2bf(v.z); o[3] = f2bf(v.w);
  *(us4*)(out + (size_t)g * 4) = o;
}

// ------- transpose + cast all 4 weights: W (K x N fp32) -> WT (N x K bf16), z picks W -------
__global__ __launch_bounds__(256) void k_transpose_cast4(const float* __restrict__ W0,
                                                         const float* __restrict__ W1,
                                                         const float* __restrict__ W2,
                                                         const float* __restrict__ W3,
                                                         ushort_t* __restrict__ WTbase) {
  __shared__ __align__(16) ushort_t ts[64 * 72];
  const float* Ws[4] = {W0, W1, W2, W3};
  const float* W = Ws[blockIdx.z];
  ushort_t* WT = WTbase + (size_t)blockIdx.z * DMODEL * DMODEL;
  const int tid = threadIdx.x;
  const int n0 = blockIdx.x * 64, k0 = blockIdx.y * 64;
  #pragma unroll
  for (int it = 0; it < 4; ++it) {
    int e = it * 256 + tid;
    int r = e >> 4, c4 = e & 15;
    float4 v = *(const float4*)(W + (size_t)(k0 + r) * DMODEL + n0 + c4 * 4);
    us4 o; o[0] = f2bf(v.x); o[1] = f2bf(v.y); o[2] = f2bf(v.z); o[3] = f2bf(v.w);
    *(us4*)&ts[r * 72 + c4 * 4] = o;
  }
  __syncthreads();
  #pragma unroll
  for (int it = 0; it < 4; ++it) {
    int e = it * 256 + tid;
    int r2 = e >> 4, c4 = e & 15;
    us4 o;
    #pragma unroll
    for (int j = 0; j < 4; ++j) o[j] = ts[(c4 * 4 + j) * 72 + r2];
    *(us4*)(WT + (size_t)(n0 + r2) * DMODEL + k0 + c4 * 4) = o;
  }
}

// ---------------- 256x256 GEMM: C[M,N] = A[M,K] @ Bt[N,K]^T ----------------
// 2-cluster schedule, 4 barriers/K-tile: reads A0+B0+B1 -> bar -> 32 MFMA ->
// read A1 (reg reuse) -> bar -> 32 MFMA -> bar -> stage t+2 -> vmcnt(8) -> bar.
// Optional fused RoPE epilogue (rows are time t, cols are h*128+hd).
template <bool OUT_BF16, bool ROPE>
__global__ __launch_bounds__(512, 2)
void k_gemm256(const ushort_t* __restrict__ A, const ushort_t* __restrict__ Bt,
               void* __restrict__ Cv, int M, int N, int K,
               const float* __restrict__ fc, const float* __restrict__ fs) {
  __shared__ __align__(16) ushort_t As[2][256 * 64];
  __shared__ __align__(16) ushort_t Bs[2][256 * 64];
  const int tid = threadIdx.x;
  const int w = tid >> 6, l = tid & 63;
  const int wr = w >> 2, wc = w & 3;
  const int lg = l >> 4, lc = l & 15;

  const int nwg = gridDim.x;
  const int cpx = nwg >> 3;
  const int wg = (blockIdx.x & 7) * cpx + (blockIdx.x >> 3);
  const int nbn = N >> 8;
  const int bm = wg / nbn, bn = wg % nbn;

  const int rowoff = l >> 3;
  const int swzck  = (l & 7) ^ rowoff;
  const ushort_t* Ab = A + (size_t)(bm * 256) * K;
  const ushort_t* Bb = Bt + (size_t)(bn * 256) * K;
  const ushort_t* gA[4]; const ushort_t* gB[4];
  int ldsOff[4];
  #pragma unroll
  for (int j = 0; j < 4; ++j) {
    int r0 = (w * 4 + j) * 8;
    gA[j] = Ab + (size_t)(r0 + rowoff) * K + swzck * 8;
    gB[j] = Bb + (size_t)(r0 + rowoff) * K + swzck * 8;
    ldsOff[j] = r0 * 64;
  }

  int offA[8][2], offB[4][2];
  #pragma unroll
  for (int m = 0; m < 8; ++m)
    #pragma unroll
    for (int kk = 0; kk < 2; ++kk)
      offA[m][kk] = (wr * 128 + m * 16 + lc) * 64 + (((kk * 4 + lg) ^ (lc & 7)) * 8);
  #pragma unroll
  for (int n = 0; n < 4; ++n)
    #pragma unroll
    for (int kk = 0; kk < 2; ++kk)
      offB[n][kk] = (wc * 64 + n * 16 + lc) * 64 + (((kk * 4 + lg) ^ (lc & 7)) * 8);

  f32x4 acc[8][4];
  #pragma unroll
  for (int m = 0; m < 8; ++m)
    #pragma unroll
    for (int n = 0; n < 4; ++n) acc[m][n] = (f32x4){0.f, 0.f, 0.f, 0.f};

  #pragma unroll
  for (int j = 0; j < 4; ++j) {
    gload_lds16(gA[j], &As[0][ldsOff[j]]);
    gload_lds16(gB[j], &Bs[0][ldsOff[j]]);
  }
  #pragma unroll
  for (int j = 0; j < 4; ++j) {
    gload_lds16(gA[j] + 64, &As[1][ldsOff[j]]);
    gload_lds16(gB[j] + 64, &Bs[1][ldsOff[j]]);
  }
  asm volatile("s_waitcnt vmcnt(8)" ::: "memory");
  __builtin_amdgcn_s_barrier();
  __builtin_amdgcn_sched_barrier(0);

  const int NT = K >> 6;
  for (int t = 0; t < NT; ++t) {
    const int cur = t & 1;
    const ushort_t* Ac = As[cur];
    const ushort_t* Bc = Bs[cur];
    bf16x8 af[4][2], b0[2][2], b1[2][2];

    // front-loaded reads: A-half0 (8) + B-half0 (4) + B-half1 (4)
    #pragma unroll
    for (int i = 0; i < 4; ++i)
      #pragma unroll
      for (int kk = 0; kk < 2; ++kk)
        af[i][kk] = *(const bf16x8*)&Ac[offA[i][kk]];
    #pragma unroll
    for (int j2 = 0; j2 < 2; ++j2)
      #pragma unroll
      for (int kk = 0; kk < 2; ++kk) {
        b0[j2][kk] = *(const bf16x8*)&Bc[offB[j2][kk]];
        b1[j2][kk] = *(const bf16x8*)&Bc[offB[2 + j2][kk]];
      }
    asm volatile("" ::: "memory");
    __builtin_amdgcn_s_barrier();

    // cluster 0: 32 MFMA (A0 x B0, A0 x B1)
    __builtin_amdgcn_s_setprio(1);
    #pragma unroll
    for (int i = 0; i < 4; ++i)
      #pragma unroll
      for (int j2 = 0; j2 < 2; ++j2)
        #pragma unroll
        for (int kk = 0; kk < 2; ++kk) {
          acc[i][j2]     = __builtin_amdgcn_mfma_f32_16x16x32_bf16(af[i][kk], b0[j2][kk], acc[i][j2], 0, 0, 0);
          acc[i][2 + j2] = __builtin_amdgcn_mfma_f32_16x16x32_bf16(af[i][kk], b1[j2][kk], acc[i][2 + j2], 0, 0, 0);
        }
    __builtin_amdgcn_s_setprio(0);

    // read A-half1 into the same registers (WAR keeps ordering after cluster 0)
    #pragma unroll
    for (int i = 0; i < 4; ++i)
      #pragma unroll
      for (int kk = 0; kk < 2; ++kk)
        af[i][kk] = *(const bf16x8*)&Ac[offA[4 + i][kk]];
    asm volatile("" ::: "memory");
    __builtin_amdgcn_s_barrier();

    // cluster 1: 32 MFMA (A1 x B0, A1 x B1)
    __builtin_amdgcn_s_setprio(1);
    #pragma unroll
    for (int i = 0; i < 4; ++i)
      #pragma unroll
      for (int j2 = 0; j2 < 2; ++j2)
        #pragma unroll
        for (int kk = 0; kk < 2; ++kk) {
          acc[4 + i][j2]     = __builtin_amdgcn_mfma_f32_16x16x32_bf16(af[i][kk], b0[j2][kk], acc[4 + i][j2], 0, 0, 0);
          acc[4 + i][2 + j2] = __builtin_amdgcn_mfma_f32_16x16x32_bf16(af[i][kk], b1[j2][kk], acc[4 + i][2 + j2], 0, 0, 0);
        }
    __builtin_amdgcn_s_setprio(0);
    asm volatile("" ::: "memory");
    __builtin_amdgcn_s_barrier();   // all waves' reads of buf[cur] are complete past here

    // stage tile t+2 into freed buffer; counted wait so t+1 is landed
    if (t + 2 < NT) {
      const int k0 = (t + 2) << 6;
      #pragma unroll
      for (int j = 0; j < 4; ++j) {
        gload_lds16(gA[j] + k0, &As[cur][ldsOff[j]]);
        gload_lds16(gB[j] + k0, &Bs[cur][ldsOff[j]]);
      }
      asm volatile("s_waitcnt vmcnt(8)" ::: "memory");
    } else if (t + 1 < NT) {
      asm volatile("s_waitcnt vmcnt(0)" ::: "memory");
    }
    if (t + 1 < NT) {
      __builtin_amdgcn_s_barrier();
      __builtin_amdgcn_sched_barrier(0);
    }
  }

  // ---- epilogue (optional fused RoPE in fp32) ----
  #pragma unroll
  for (int m = 0; m < 8; ++m) {
    int row0 = bm * 256 + wr * 128 + m * 16 + lg * 4;
    #pragma unroll
    for (int n = 0; n < 4; ++n) {
      int col = bn * 256 + wc * 64 + n * 16 + lc;
      if (ROPE) {
        int i0 = (col & 127) >> 1;
        #pragma unroll
        for (int r = 0; r < 4; ++r) {
          int tt = (row0 + r) & (TSEQ - 1);
          float c = fc[tt * 64 + i0];
          float s = fs[tt * 64 + i0];
          float v = acc[m][n][r];
          float p = __shfl_xor(v, 1);
          float ov = (lc & 1) ? (p * s + v * c) : (v * c - p * s);
          ((ushort_t*)Cv)[(size_t)(row0 + r) * N + col] = f2bf(ov);
        }
      } else {
        #pragma unroll
        for (int r = 0; r < 4; ++r) {
          float v = acc[m][n][r];
          if (OUT_BF16) ((ushort_t*)Cv)[(size_t)(row0 + r) * N + col] = f2bf(v);
          else          ((float*)Cv)[(size_t)(row0 + r) * N + col] = v;
        }
      }
    }
  }
}

// ---------------- causal flash attention, QBLK=128, 8 waves ----------------
// Double-buffered DMA staging (global_load_lds, pre-swizzled source), counted vmcnt(4).
// XCD-grouped block swizzle; T13 defer-max; deferred l-reduction; wave-skip.
__global__ __launch_bounds__(512, 2)
void k_attn(const ushort_t* __restrict__ Q, const ushort_t* __restrict__ Kb,
            const ushort_t* __restrict__ Vt, ushort_t* __restrict__ Y) {
  __shared__ __align__(16) ushort_t Ks[2][64 * 128];
  __shared__ __align__(16) ushort_t Vs[2][128 * 64];
  __shared__ __align__(16) ushort_t Ps[8][16 * 64];
  const int id = blockIdx.x;
  const int xcd = id & 7, slot = id >> 3;
  const int bx = slot & 7, gHi = slot >> 3;
  const int g = gHi * 8 + xcd;
  const int h = g & 31, b = g >> 5;
  const int tid = threadIdx.x;
  const int w = tid >> 6, l = tid & 63;
  const int lg = l >> 4, lc = l & 15;
  const float scale = 0.08838834764831845f;  // 1/sqrt(128)
  const float THR = 8.0f;

  auto stageKV = [&](int kv0, int buf) {
    #pragma unroll
    for (int i = 0; i < 2; ++i) {
      int seg = w * 2 + i;
      {
        int row = seg * 4 + (l >> 4);
        int csrc = (l & 15) ^ (row & 7);
        gload_lds16(Kb + (size_t)(b * TSEQ + kv0 + row) * DMODEL + h * 128 + csrc * 8,
                    &Ks[buf][seg * 512]);
      }
      {
        int row = seg * 8 + (l >> 3);
        int csrc = (l & 7) ^ (l >> 3);
        gload_lds16(Vt + (size_t)(h * 128 + row) * DMODEL + b * TSEQ + kv0 + csrc * 8,
                    &Vs[buf][seg * 512]);
      }
    }
  };

  for (int qi = 0; qi < 2; ++qi) {
    const int qt = qi ? (15 - bx) : bx;
    const int q0 = qt * 128;
    const int wrow0 = q0 + w * 16;

    bf16x8 qf[4];
    {
      const ushort_t* qp = Q + (size_t)(b * TSEQ + wrow0 + lc) * DMODEL + h * 128;
      #pragma unroll
      for (int ks = 0; ks < 4; ++ks) qf[ks] = *(const bf16x8*)(qp + ks * 32 + lg * 8);
    }

    float m_r[4], lp[4];
    #pragma unroll
    for (int r = 0; r < 4; ++r) { m_r[r] = -1e30f; lp[r] = 0.f; }
    f32x4 o[8];
    #pragma unroll
    for (int t = 0; t < 8; ++t) o[t] = (f32x4){0.f, 0.f, 0.f, 0.f};

    const int nkv = (qt + 1) * 2;
    stageKV(0, 0);
    for (int kt = 0; kt < nkv; ++kt) {
      const int cur = kt & 1;
      const int kv0 = kt * 64;
      if (kt + 1 < nkv) {
        stageKV((kt + 1) * 64, cur ^ 1);
        asm volatile("s_waitcnt vmcnt(4)" ::: "memory");
      } else {
        asm volatile("s_waitcnt vmcnt(0)" ::: "memory");
      }
      __builtin_amdgcn_s_barrier();

      if (kv0 <= wrow0 + 15) {
        f32x4 s[4];
        __builtin_amdgcn_s_setprio(1);
        #pragma unroll
        for (int n = 0; n < 4; ++n) {
          s[n] = (f32x4){0.f, 0.f, 0.f, 0.f};
          #pragma unroll
          for (int ks = 0; ks < 4; ++ks) {
            int row = n * 16 + lc;
            bf16x8 kf = *(const bf16x8*)&Ks[cur][row * 128 + ((ks * 32 + lg * 8) ^ ((row & 7) * 8))];
            s[n] = __builtin_amdgcn_mfma_f32_16x16x32_bf16(qf[ks], kf, s[n], 0, 0, 0);
          }
        }
        __builtin_amdgcn_s_setprio(0);

        float sv[4][4];
        if (kv0 + 63 > wrow0) {
          #pragma unroll
          for (int n = 0; n < 4; ++n)
            #pragma unroll
            for (int r = 0; r < 4; ++r) {
              float x = s[n][r] * scale;
              int kvg = kv0 + n * 16 + lc;
              int qg = wrow0 + lg * 4 + r;
              sv[n][r] = (kvg > qg) ? -1e30f : x;
            }
        } else {
          #pragma unroll
          for (int n = 0; n < 4; ++n)
            #pragma unroll
            for (int r = 0; r < 4; ++r) sv[n][r] = s[n][r] * scale;
        }

        float pmax[4];
        #pragma unroll
        for (int r = 0; r < 4; ++r)
          pmax[r] = fmaxf(fmaxf(sv[0][r], sv[1][r]), fmaxf(sv[2][r], sv[3][r]));
        bool ok = (pmax[0] <= m_r[0] + THR) && (pmax[1] <= m_r[1] + THR) &&
                  (pmax[2] <= m_r[2] + THR) && (pmax[3] <= m_r[3] + THR);
        if (!__all(ok)) {
          #pragma unroll
          for (int r = 0; r < 4; ++r) {
            float mx = pmax[r];
            #pragma unroll
            for (int off = 1; off < 16; off <<= 1) mx = fmaxf(mx, __shfl_xor(mx, off, 16));
            float mn = fmaxf(m_r[r], mx);
            float al = __expf(m_r[r] - mn);
            m_r[r] = mn;
            lp[r] *= al;
            #pragma unroll
            for (int t = 0; t < 8; ++t) o[t][r] *= al;
          }
        }

        #pragma unroll
        for (int n = 0; n < 4; ++n)
          #pragma unroll
          for (int r = 0; r < 4; ++r) {
            float p = __expf(sv[n][r] - m_r[r]);
            lp[r] += p;
            int row = lg * 4 + r, col = n * 16 + lc;
            Ps[w][row * 64 + (col ^ (lg * 16))] = f2bf(p);
          }

        __builtin_amdgcn_s_setprio(1);
        #pragma unroll
        for (int kvs = 0; kvs < 2; ++kvs) {
          bf16x8 pa = *(const bf16x8*)&Ps[w][lc * 64 + ((kvs * 32 + lg * 8) ^ ((lc >> 2) * 16))];
          #pragma unroll
          for (int t = 0; t < 8; ++t) {
            int vrow = t * 16 + lc;
            bf16x8 vb = *(const bf16x8*)&Vs[cur][vrow * 64 + ((kvs * 32 + lg * 8) ^ ((vrow & 7) * 8))];
            o[t] = __builtin_amdgcn_mfma_f32_16x16x32_bf16(pa, vb, o[t], 0, 0, 0);
          }
        }
        __builtin_amdgcn_s_setprio(0);
      }
      asm volatile("" ::: "memory");
      __builtin_amdgcn_s_barrier();
    }

    float linv[4];
    #pragma unroll
    for (int r = 0; r < 4; ++r) {
      float ls = lp[r];
      #pragma unroll
      for (int off = 1; off < 16; off <<= 1) ls += __shfl_xor(ls, off, 16);
      linv[r] = 1.0f / ls;
    }

    #pragma unroll
    for (int t = 0; t < 8; ++t)
      #pragma unroll
      for (int r = 0; r < 4; ++r) {
        int row = wrow0 + lg * 4 + r;
        int col = h * 128 + t * 16 + lc;
        Y[(size_t)(b * TSEQ + row) * DMODEL + col] = f2bf(o[t][r] * linv[r]);
      }
  }
}

extern "C" void kernel_launch(void* const* d_in, const int* in_sizes, int n_in,
                              void* d_out, int out_size, void* d_ws, size_t ws_size,
                              hipStream_t stream) {
  const float* x  = (const float*)d_in[0];
  const float* fc = (const float*)d_in[1];
  const float* fs = (const float*)d_in[2];
  const float* Wq = (const float*)d_in[3];
  const float* Wk = (const float*)d_in[4];
  const float* Wv = (const float*)d_in[5];
  const float* Wo = (const float*)d_in[6];

  const size_t SZ = (size_t)4096 * 4096;
  ushort_t* xb  = (ushort_t*)d_ws;
  ushort_t* WqT = xb + SZ;
  ushort_t* WkT = WqT + SZ;
  ushort_t* WvT = WkT + SZ;
  ushort_t* WoT = WvT + SZ;
  ushort_t* qb  = WoT + SZ;
  ushort_t* kb  = qb + SZ;
  ushort_t* vT  = kb + SZ;
  ushort_t* yb  = vT + SZ;

  k_cast_bf16<<<16384, 256, 0, stream>>>(x, xb, 4194304);
  dim3 tg(64, 64, 4);
  k_transpose_cast4<<<tg, 256, 0, stream>>>(Wq, Wk, Wv, Wo, WqT);

  k_gemm256<true, true><<<256, 512, 0, stream>>>(xb, WqT, qb, 4096, 4096, 4096, fc, fs);
  k_gemm256<true, true><<<256, 512, 0, stream>>>(xb, WkT, kb, 4096, 4096, 4096, fc, fs);
  // V^T directly: vT[hd][t] = sum_k WvT[hd][k] * xb[t][k]
  k_gemm256<true, false><<<256, 512, 0, stream>>>(WvT, xb, vT, 4096, 4096, 4096, nullptr, nullptr);

  k_attn<<<512, 512, 0, stream>>>(qb, kb, vT, yb);

  k_gemm256<false, false><<<256, 512, 0, stream>>>(yb, WoT, d_out, 4096, 4096, 4096, nullptr, nullptr);
}

// Round 7
// 859.376 us; speedup vs baseline: 1.0502x; 1.0502x over previous
//
#include <hip/hip_runtime.h>

typedef unsigned short ushort_t;
typedef unsigned int uint32;

typedef float f32x4 __attribute__((ext_vector_type(4)));
typedef __bf16 bf16x8 __attribute__((ext_vector_type(8)));
typedef unsigned short us8 __attribute__((ext_vector_type(8)));
typedef unsigned short us4 __attribute__((ext_vector_type(4)));

#define TSEQ 2048
#define DMODEL 4096

__device__ __forceinline__ ushort_t f2bf(float f) {
  uint32 u = __builtin_bit_cast(uint32, f);
  u += 0x7FFFu + ((u >> 16) & 1u);   // RNE (no NaNs in this problem)
  return (ushort_t)(u >> 16);
}
__device__ __forceinline__ float bf2f(ushort_t u) {
  return __builtin_bit_cast(float, ((uint32)u) << 16);
}

__device__ __forceinline__ void gload_lds16(const void* g, void* l) {
  auto gp = (const __attribute__((address_space(1))) void*)g;
  auto lp = (__attribute__((address_space(3))) void*)l;
  __builtin_amdgcn_global_load_lds(gp, lp, 16, 0, 0);
}

// ---------------- cast fp32 -> bf16 (vectorized) ----------------
__global__ __launch_bounds__(256) void k_cast_bf16(const float* __restrict__ in,
                                                   ushort_t* __restrict__ out, int n4) {
  int g = blockIdx.x * 256 + threadIdx.x;
  if (g >= n4) return;
  float4 v = *(const float4*)(in + (size_t)g * 4);
  us4 o; o[0] = f2bf(v.x); o[1] = f2bf(v.y); o[2] = f2bf(v.z); o[3] = f2bf(v.w);
  *(us4*)(out + (size_t)g * 4) = o;
}

// ------- transpose + cast all 4 weights: W (K x N fp32) -> WT (N x K bf16), z picks W -------
__global__ __launch_bounds__(256) void k_transpose_cast4(const float* __restrict__ W0,
                                                         const float* __restrict__ W1,
                                                         const float* __restrict__ W2,
                                                         const float* __restrict__ W3,
                                                         ushort_t* __restrict__ WTbase) {
  __shared__ __align__(16) ushort_t ts[64 * 72];
  const float* Ws[4] = {W0, W1, W2, W3};
  const float* W = Ws[blockIdx.z];
  ushort_t* WT = WTbase + (size_t)blockIdx.z * DMODEL * DMODEL;
  const int tid = threadIdx.x;
  const int n0 = blockIdx.x * 64, k0 = blockIdx.y * 64;
  #pragma unroll
  for (int it = 0; it < 4; ++it) {
    int e = it * 256 + tid;
    int r = e >> 4, c4 = e & 15;
    float4 v = *(const float4*)(W + (size_t)(k0 + r) * DMODEL + n0 + c4 * 4);
    us4 o; o[0] = f2bf(v.x); o[1] = f2bf(v.y); o[2] = f2bf(v.z); o[3] = f2bf(v.w);
    *(us4*)&ts[r * 72 + c4 * 4] = o;
  }
  __syncthreads();
  #pragma unroll
  for (int it = 0; it < 4; ++it) {
    int e = it * 256 + tid;
    int r2 = e >> 4, c4 = e & 15;
    us4 o;
    #pragma unroll
    for (int j = 0; j < 4; ++j) o[j] = ts[(c4 * 4 + j) * 72 + r2];
    *(us4*)(WT + (size_t)(n0 + r2) * DMODEL + k0 + c4 * 4) = o;
  }
}

// ---------------- 256x256 8-phase GEMM (m201 port): C = A @ Bt^T ----------------
// 8 waves (2M x 4N). 2 K-tiles/iter, 8 phases x 16 MFMA. Half-tile staging
// (2 gload_lds/wave/phase) one-phase-after-death; vmcnt(6) before ph3/ph7
// closing barriers only. lgkmcnt(0)+sched_barrier(0) after each pre-MFMA barrier.
template <bool OUT_BF16, bool ROPE>
__global__ __launch_bounds__(512, 2)
void k_gemm256(const ushort_t* __restrict__ A, const ushort_t* __restrict__ Bt,
               void* __restrict__ Cv, int M, int N, int K,
               const float* __restrict__ fc, const float* __restrict__ fs) {
  __shared__ __align__(16) ushort_t As[2][256 * 64];
  __shared__ __align__(16) ushort_t Bs[2][256 * 64];
  const int tid = threadIdx.x;
  const int w = tid >> 6, l = tid & 63;
  const int wr = w >> 2, wc = w & 3;
  const int lg = l >> 4, lc = l & 15;

  // XCD-bijective swizzle (nwg % 8 == 0)
  const int nwg = gridDim.x;
  const int cpx = nwg >> 3;
  const int wg = (blockIdx.x & 7) * cpx + (blockIdx.x >> 3);
  const int nbn = N >> 8;
  const int bm = wg / nbn, bn = wg % nbn;

  const ushort_t* Ab = A + (size_t)(bm * 256) * K;
  const ushort_t* Bb = Bt + (size_t)(bn * 256) * K;

  // staging: per-wave 2 segments (8 rows x 64 el each) per half-tile.
  // A-half0 = segs {0..7,16..23}, A-half1 = +8; B-half0 = segs {(i>>2)*8+(i&3)}, B-half1 = +4.
  int aS0[2], aS1[2], bS0[2], bS1[2];
  #pragma unroll
  for (int j = 0; j < 2; ++j) {
    aS0[j] = (w < 4) ? (2 * w + j) : (8 + 2 * w + j);
    aS1[j] = aS0[j] + 8;
    int i2 = 2 * w + j;
    bS0[j] = (i2 >> 2) * 8 + (i2 & 3);
    bS1[j] = bS0[j] + 4;
  }
  const int rowoff = l >> 3;
  const int swz = (l & 7) ^ rowoff;

  // read-side swizzled offsets (elements)
  int offA[8][2], offB[4][2];
  #pragma unroll
  for (int m = 0; m < 8; ++m)
    #pragma unroll
    for (int kk = 0; kk < 2; ++kk)
      offA[m][kk] = (wr * 128 + m * 16 + lc) * 64 + (((kk * 4 + lg) ^ (lc & 7)) * 8);
  #pragma unroll
  for (int n = 0; n < 4; ++n)
    #pragma unroll
    for (int kk = 0; kk < 2; ++kk)
      offB[n][kk] = (wc * 64 + n * 16 + lc) * 64 + (((kk * 4 + lg) ^ (lc & 7)) * 8);

  f32x4 acc[8][4];
  #pragma unroll
  for (int m = 0; m < 8; ++m)
    #pragma unroll
    for (int n = 0; n < 4; ++n) acc[m][n] = (f32x4){0.f, 0.f, 0.f, 0.f};

  const int NT = K >> 6;
  auto stg = [&](const ushort_t* gb, ushort_t* lds, int s, int tl) {
    int k0 = ((tl < NT) ? tl : (NT - 1)) << 6;
    gload_lds16(gb + (size_t)(s * 8 + rowoff) * K + k0 + swz * 8, lds + s * 512);
  };

  // ---- prologue: tile0 complete (8), tile1 A0,B0,B1 (6); A1@tile1 comes at first ph0 ----
  stg(Ab, As[0], aS0[0], 0); stg(Ab, As[0], aS0[1], 0);
  stg(Bb, Bs[0], bS0[0], 0); stg(Bb, Bs[0], bS0[1], 0);
  stg(Bb, Bs[0], bS1[0], 0); stg(Bb, Bs[0], bS1[1], 0);
  stg(Ab, As[0], aS1[0], 0); stg(Ab, As[0], aS1[1], 0);
  stg(Ab, As[1], aS0[0], 1); stg(Ab, As[1], aS0[1], 1);
  stg(Bb, Bs[1], bS0[0], 1); stg(Bb, Bs[1], bS0[1], 1);
  stg(Bb, Bs[1], bS1[0], 1); stg(Bb, Bs[1], bS1[1], 1);
  asm volatile("s_waitcnt vmcnt(6)" ::: "memory");
  __builtin_amdgcn_s_barrier();

  // one pass = 4 phases over one K-tile (buffer Ac/Bc).
  // phA: read A0(8)+B0(4); stage A1 -> AsOth @ tA1.  MFMA m0n0.
  // phB: read B1(4);       stage A0 -> AsCur @ tM.   MFMA m0n1.
  // phC: read A1(8, reuse);stage B0 -> BsCur @ tM.   MFMA m1n1.
  // phD: no reads;         stage B1 -> BsCur @ tM.   MFMA m1n0. vmcnt(6) + bar.
  auto pass = [&](const ushort_t* Ac, const ushort_t* Bc, ushort_t* AsOth,
                  ushort_t* AsCur, ushort_t* BsCur, int tA1, int tM) {
    bf16x8 af[4][2], b0r[2][2], b1r[2][2];
    // ---- phA ----
    #pragma unroll
    for (int i = 0; i < 4; ++i)
      #pragma unroll
      for (int kk = 0; kk < 2; ++kk)
        af[i][kk] = *(const bf16x8*)&Ac[offA[i][kk]];
    #pragma unroll
    for (int j2 = 0; j2 < 2; ++j2)
      #pragma unroll
      for (int kk = 0; kk < 2; ++kk)
        b0r[j2][kk] = *(const bf16x8*)&Bc[offB[j2][kk]];
    stg(Ab, AsOth, aS1[0], tA1); stg(Ab, AsOth, aS1[1], tA1);
    asm volatile("s_waitcnt lgkmcnt(8)" ::: "memory");
    __builtin_amdgcn_s_barrier();
    asm volatile("s_waitcnt lgkmcnt(0)" ::: "memory");
    __builtin_amdgcn_sched_barrier(0);
    __builtin_amdgcn_s_setprio(1);
    #pragma unroll
    for (int i = 0; i < 4; ++i)
      #pragma unroll
      for (int j2 = 0; j2 < 2; ++j2)
        #pragma unroll
        for (int kk = 0; kk < 2; ++kk)
          acc[i][j2] = __builtin_amdgcn_mfma_f32_16x16x32_bf16(af[i][kk], b0r[j2][kk], acc[i][j2], 0, 0, 0);
    __builtin_amdgcn_s_setprio(0);
    __builtin_amdgcn_s_barrier();

    // ---- phB ----
    #pragma unroll
    for (int j2 = 0; j2 < 2; ++j2)
      #pragma unroll
      for (int kk = 0; kk < 2; ++kk)
        b1r[j2][kk] = *(const bf16x8*)&Bc[offB[2 + j2][kk]];
    stg(Ab, AsCur, aS0[0], tM); stg(Ab, AsCur, aS0[1], tM);
    asm volatile("" ::: "memory");
    __builtin_amdgcn_s_barrier();
    asm volatile("s_waitcnt lgkmcnt(0)" ::: "memory");
    __builtin_amdgcn_sched_barrier(0);
    __builtin_amdgcn_s_setprio(1);
    #pragma unroll
    for (int i = 0; i < 4; ++i)
      #pragma unroll
      for (int j2 = 0; j2 < 2; ++j2)
        #pragma unroll
        for (int kk = 0; kk < 2; ++kk)
          acc[i][2 + j2] = __builtin_amdgcn_mfma_f32_16x16x32_bf16(af[i][kk], b1r[j2][kk], acc[i][2 + j2], 0, 0, 0);
    __builtin_amdgcn_s_setprio(0);
    __builtin_amdgcn_s_barrier();

    // ---- phC ----
    #pragma unroll
    for (int i = 0; i < 4; ++i)
      #pragma unroll
      for (int kk = 0; kk < 2; ++kk)
        af[i][kk] = *(const bf16x8*)&Ac[offA[4 + i][kk]];
    stg(Bb, BsCur, bS0[0], tM); stg(Bb, BsCur, bS0[1], tM);
    asm volatile("" ::: "memory");
    __builtin_amdgcn_s_barrier();
    asm volatile("s_waitcnt lgkmcnt(0)" ::: "memory");
    __builtin_amdgcn_sched_barrier(0);
    __builtin_amdgcn_s_setprio(1);
    #pragma unroll
    for (int i = 0; i < 4; ++i)
      #pragma unroll
      for (int j2 = 0; j2 < 2; ++j2)
        #pragma unroll
        for (int kk = 0; kk < 2; ++kk)
          acc[4 + i][2 + j2] = __builtin_amdgcn_mfma_f32_16x16x32_bf16(af[i][kk], b1r[j2][kk], acc[4 + i][2 + j2], 0, 0, 0);
    __builtin_amdgcn_s_setprio(0);
    __builtin_amdgcn_s_barrier();

    // ---- phD ----
    stg(Bb, BsCur, bS1[0], tM); stg(Bb, BsCur, bS1[1], tM);
    asm volatile("" ::: "memory");
    __builtin_amdgcn_s_barrier();
    __builtin_amdgcn_s_setprio(1);
    #pragma unroll
    for (int i = 0; i < 4; ++i)
      #pragma unroll
      for (int j2 = 0; j2 < 2; ++j2)
        #pragma unroll
        for (int kk = 0; kk < 2; ++kk)
          acc[4 + i][j2] = __builtin_amdgcn_mfma_f32_16x16x32_bf16(af[i][kk], b0r[j2][kk], acc[4 + i][j2], 0, 0, 0);
    __builtin_amdgcn_s_setprio(0);
    asm volatile("s_waitcnt vmcnt(6)" ::: "memory");
    __builtin_amdgcn_s_barrier();
  };

  for (int t2 = 0; t2 < NT; t2 += 2) {
    pass(As[0], Bs[0], As[1], As[0], Bs[0], t2 + 1, t2 + 2);
    pass(As[1], Bs[1], As[0], As[1], Bs[1], t2 + 2, t2 + 3);
  }

  // ---- epilogue (optional fused RoPE in fp32) ----
  #pragma unroll
  for (int m = 0; m < 8; ++m) {
    int row0 = bm * 256 + wr * 128 + m * 16 + lg * 4;
    #pragma unroll
    for (int n = 0; n < 4; ++n) {
      int col = bn * 256 + wc * 64 + n * 16 + lc;
      if (ROPE) {
        int i0 = (col & 127) >> 1;
        #pragma unroll
        for (int r = 0; r < 4; ++r) {
          int tt = (row0 + r) & (TSEQ - 1);
          float c = fc[tt * 64 + i0];
          float s = fs[tt * 64 + i0];
          float v = acc[m][n][r];
          float p = __shfl_xor(v, 1);
          float ov = (lc & 1) ? (p * s + v * c) : (v * c - p * s);
          ((ushort_t*)Cv)[(size_t)(row0 + r) * N + col] = f2bf(ov);
        }
      } else {
        #pragma unroll
        for (int r = 0; r < 4; ++r) {
          float v = acc[m][n][r];
          if (OUT_BF16) ((ushort_t*)Cv)[(size_t)(row0 + r) * N + col] = f2bf(v);
          else          ((float*)Cv)[(size_t)(row0 + r) * N + col] = v;
        }
      }
    }
  }
}

// ---------------- causal flash attention, QBLK=128, 8 waves ----------------
__global__ __launch_bounds__(512, 2)
void k_attn(const ushort_t* __restrict__ Q, const ushort_t* __restrict__ Kb,
            const ushort_t* __restrict__ Vt, ushort_t* __restrict__ Y) {
  __shared__ __align__(16) ushort_t Ks[2][64 * 128];
  __shared__ __align__(16) ushort_t Vs[2][128 * 64];
  __shared__ __align__(16) ushort_t Ps[8][16 * 64];
  const int id = blockIdx.x;
  const int xcd = id & 7, slot = id >> 3;
  const int bx = slot & 7, gHi = slot >> 3;
  const int g = gHi * 8 + xcd;
  const int h = g & 31, b = g >> 5;
  const int tid = threadIdx.x;
  const int w = tid >> 6, l = tid & 63;
  const int lg = l >> 4, lc = l & 15;
  const float scale = 0.08838834764831845f;  // 1/sqrt(128)
  const float THR = 8.0f;

  auto stageKV = [&](int kv0, int buf) {
    #pragma unroll
    for (int i = 0; i < 2; ++i) {
      int seg = w * 2 + i;
      {
        int row = seg * 4 + (l >> 4);
        int csrc = (l & 15) ^ (row & 7);
        gload_lds16(Kb + (size_t)(b * TSEQ + kv0 + row) * DMODEL + h * 128 + csrc * 8,
                    &Ks[buf][seg * 512]);
      }
      {
        int row = seg * 8 + (l >> 3);
        int csrc = (l & 7) ^ (l >> 3);
        gload_lds16(Vt + (size_t)(h * 128 + row) * DMODEL + b * TSEQ + kv0 + csrc * 8,
                    &Vs[buf][seg * 512]);
      }
    }
  };

  for (int qi = 0; qi < 2; ++qi) {
    const int qt = qi ? (15 - bx) : bx;
    const int q0 = qt * 128;
    const int wrow0 = q0 + w * 16;

    bf16x8 qf[4];
    {
      const ushort_t* qp = Q + (size_t)(b * TSEQ + wrow0 + lc) * DMODEL + h * 128;
      #pragma unroll
      for (int ks = 0; ks < 4; ++ks) qf[ks] = *(const bf16x8*)(qp + ks * 32 + lg * 8);
    }

    float m_r[4], lp[4];
    #pragma unroll
    for (int r = 0; r < 4; ++r) { m_r[r] = -1e30f; lp[r] = 0.f; }
    f32x4 o[8];
    #pragma unroll
    for (int t = 0; t < 8; ++t) o[t] = (f32x4){0.f, 0.f, 0.f, 0.f};

    const int nkv = (qt + 1) * 2;
    stageKV(0, 0);
    for (int kt = 0; kt < nkv; ++kt) {
      const int cur = kt & 1;
      const int kv0 = kt * 64;
      if (kt + 1 < nkv) {
        stageKV((kt + 1) * 64, cur ^ 1);
        asm volatile("s_waitcnt vmcnt(4)" ::: "memory");
      } else {
        asm volatile("s_waitcnt vmcnt(0)" ::: "memory");
      }
      __builtin_amdgcn_s_barrier();

      if (kv0 <= wrow0 + 15) {
        f32x4 s[4];
        __builtin_amdgcn_s_setprio(1);
        #pragma unroll
        for (int n = 0; n < 4; ++n) {
          s[n] = (f32x4){0.f, 0.f, 0.f, 0.f};
          #pragma unroll
          for (int ks = 0; ks < 4; ++ks) {
            int row = n * 16 + lc;
            bf16x8 kf = *(const bf16x8*)&Ks[cur][row * 128 + ((ks * 32 + lg * 8) ^ ((row & 7) * 8))];
            s[n] = __builtin_amdgcn_mfma_f32_16x16x32_bf16(qf[ks], kf, s[n], 0, 0, 0);
          }
        }
        __builtin_amdgcn_s_setprio(0);

        float sv[4][4];
        if (kv0 + 63 > wrow0) {
          #pragma unroll
          for (int n = 0; n < 4; ++n)
            #pragma unroll
            for (int r = 0; r < 4; ++r) {
              float x = s[n][r] * scale;
              int kvg = kv0 + n * 16 + lc;
              int qg = wrow0 + lg * 4 + r;
              sv[n][r] = (kvg > qg) ? -1e30f : x;
            }
        } else {
          #pragma unroll
          for (int n = 0; n < 4; ++n)
            #pragma unroll
            for (int r = 0; r < 4; ++r) sv[n][r] = s[n][r] * scale;
        }

        float pmax[4];
        #pragma unroll
        for (int r = 0; r < 4; ++r)
          pmax[r] = fmaxf(fmaxf(sv[0][r], sv[1][r]), fmaxf(sv[2][r], sv[3][r]));
        bool ok = (pmax[0] <= m_r[0] + THR) && (pmax[1] <= m_r[1] + THR) &&
                  (pmax[2] <= m_r[2] + THR) && (pmax[3] <= m_r[3] + THR);
        if (!__all(ok)) {
          #pragma unroll
          for (int r = 0; r < 4; ++r) {
            float mx = pmax[r];
            #pragma unroll
            for (int off = 1; off < 16; off <<= 1) mx = fmaxf(mx, __shfl_xor(mx, off, 16));
            float mn = fmaxf(m_r[r], mx);
            float al = __expf(m_r[r] - mn);
            m_r[r] = mn;
            lp[r] *= al;
            #pragma unroll
            for (int t = 0; t < 8; ++t) o[t][r] *= al;
          }
        }

        #pragma unroll
        for (int n = 0; n < 4; ++n)
          #pragma unroll
          for (int r = 0; r < 4; ++r) {
            float p = __expf(sv[n][r] - m_r[r]);
            lp[r] += p;
            int row = lg * 4 + r, col = n * 16 + lc;
            Ps[w][row * 64 + (col ^ (lg * 16))] = f2bf(p);
          }

        __builtin_amdgcn_s_setprio(1);
        #pragma unroll
        for (int kvs = 0; kvs < 2; ++kvs) {
          bf16x8 pa = *(const bf16x8*)&Ps[w][lc * 64 + ((kvs * 32 + lg * 8) ^ ((lc >> 2) * 16))];
          #pragma unroll
          for (int t = 0; t < 8; ++t) {
            int vrow = t * 16 + lc;
            bf16x8 vb = *(const bf16x8*)&Vs[cur][vrow * 64 + ((kvs * 32 + lg * 8) ^ ((vrow & 7) * 8))];
            o[t] = __builtin_amdgcn_mfma_f32_16x16x32_bf16(pa, vb, o[t], 0, 0, 0);
          }
        }
        __builtin_amdgcn_s_setprio(0);
      }
      asm volatile("" ::: "memory");
      __builtin_amdgcn_s_barrier();
    }

    float linv[4];
    #pragma unroll
    for (int r = 0; r < 4; ++r) {
      float ls = lp[r];
      #pragma unroll
      for (int off = 1; off < 16; off <<= 1) ls += __shfl_xor(ls, off, 16);
      linv[r] = 1.0f / ls;
    }

    #pragma unroll
    for (int t = 0; t < 8; ++t)
      #pragma unroll
      for (int r = 0; r < 4; ++r) {
        int row = wrow0 + lg * 4 + r;
        int col = h * 128 + t * 16 + lc;
        Y[(size_t)(b * TSEQ + row) * DMODEL + col] = f2bf(o[t][r] * linv[r]);
      }
  }
}

extern "C" void kernel_launch(void* const* d_in, const int* in_sizes, int n_in,
                              void* d_out, int out_size, void* d_ws, size_t ws_size,
                              hipStream_t stream) {
  const float* x  = (const float*)d_in[0];
  const float* fc = (const float*)d_in[1];
  const float* fs = (const float*)d_in[2];
  const float* Wq = (const float*)d_in[3];
  const float* Wk = (const float*)d_in[4];
  const float* Wv = (const float*)d_in[5];
  const float* Wo = (const float*)d_in[6];

  const size_t SZ = (size_t)4096 * 4096;
  ushort_t* xb  = (ushort_t*)d_ws;
  ushort_t* WqT = xb + SZ;
  ushort_t* WkT = WqT + SZ;
  ushort_t* WvT = WkT + SZ;
  ushort_t* WoT = WvT + SZ;
  ushort_t* qb  = WoT + SZ;
  ushort_t* kb  = qb + SZ;
  ushort_t* vT  = kb + SZ;
  ushort_t* yb  = vT + SZ;

  k_cast_bf16<<<16384, 256, 0, stream>>>(x, xb, 4194304);
  dim3 tg(64, 64, 4);
  k_transpose_cast4<<<tg, 256, 0, stream>>>(Wq, Wk, Wv, Wo, WqT);

  k_gemm256<true, true><<<256, 512, 0, stream>>>(xb, WqT, qb, 4096, 4096, 4096, fc, fs);
  k_gemm256<true, true><<<256, 512, 0, stream>>>(xb, WkT, kb, 4096, 4096, 4096, fc, fs);
  // V^T directly: vT[hd][t] = sum_k WvT[hd][k] * xb[t][k]
  k_gemm256<true, false><<<256, 512, 0, stream>>>(WvT, xb, vT, 4096, 4096, 4096, nullptr, nullptr);

  k_attn<<<512, 512, 0, stream>>>(qb, kb, vT, yb);

  k_gemm256<false, false><<<256, 512, 0, stream>>>(yb, WoT, d_out, 4096, 4096, 4096, nullptr, nullptr);
}